// Round 5
// baseline (179.124 us; speedup 1.0000x reference)
//
#include <hip/hip_runtime.h>
#include <math.h>

#define N_NODES 15000
#define NPAD    15008          // 938 node-groups * 16
#define N_EDGES 300000
#define NCH     128
#define RHO_STRIDE 1152        // 9*128
#define OUT_COLS 528           // 16 + 128 + 3*128
#define ES      300032         // padded edge count (mult of 32)
#define NCHUNK  (ES / 32)      // 9376
#define CHROWS  72             // rows per chunk in AYt (72 real)

typedef _Float16 half8   __attribute__((ext_vector_type(8)));
typedef short    short8  __attribute__((ext_vector_type(8)));
typedef float    floatx4 __attribute__((ext_vector_type(4)));

// ---- workspace layout ----
#define RHO16_BYTES ((size_t)NPAD * RHO_STRIDE * 2)          // 34,578,432
#define WT_OFF      RHO16_BYTES
#define WT_BYTES    (3 * 256 * 128 * 2)                      // 196,608
#define RP_OFF      (WT_OFF + WT_BYTES)
#define RP_BYTES    61440
#define SPE_OFF     (RP_OFF + RP_BYTES)
#define SPE_BYTES   ((size_t)ES * 2)                         // 600,064
#define AYT_OFF     (SPE_OFF + SPE_BYTES)
#define AYT_BYTES   ((size_t)NCHUNK * CHROWS * 32 * 2 + 4096) // 43,208,704 (+pad for tile-4 overread)
#define WS_NEEDED   (AYT_OFF + AYT_BYTES)                    // ~78.6 MB

// block-role boundaries for fused prep kernel
#define PREP_EDGE_BLOCKS 1172          // ceil(300000/256)
#define PREP_WT_BLOCKS   384           // 98304/256
#define PREP_RP_BLOCKS   59            // ceil(15009/256)
#define PREP_BLOCKS (PREP_EDGE_BLOCKS + PREP_WT_BLOCKS + PREP_RP_BLOCKS)

// ---------- fused prep: edge geometry -> AYt/spE | Wt transpose | row_ptr ----------
__global__ __launch_bounds__(256) void prep_kernel(
    const float* __restrict__ dist, const float* __restrict__ vec,
    const float* __restrict__ sw,   const int* __restrict__ species,
    const int* __restrict__ edst,   const int* __restrict__ esrc,
    const float* __restrict__ W0, const float* __restrict__ W1,
    const float* __restrict__ W2,
    _Float16* __restrict__ AYt, short* __restrict__ spE,
    _Float16* __restrict__ Wt,  int* __restrict__ row_ptr)
{
    const int b = blockIdx.x, tid = threadIdx.x;
    if (b < PREP_EDGE_BLOCKS) {
        int e = b * 256 + tid;
        if (e >= N_EDGES) return;

        const float bnorm = 0.6324555320336759f;   // sqrt(2/cutoff)
        const float s3  = 1.7320508075688772f;
        const float s5  = 2.2360679774997896f;
        const float s15 = 3.872983346207417f;
        const float cstep = 3.14159265358979323846f / 5.0f;

        float r    = dist[e];
        float invr = 1.0f / r;
        float g    = bnorm * invr * sw[e];
        float x = vec[3*e+0] * invr;
        float y = vec[3*e+1] * invr;
        float z = vec[3*e+2] * invr;

        spE[e] = (short)species[edst[e]];

        float f[8];
        #pragma unroll
        for (int n = 0; n < 8; ++n)
            f[n] = g * __sinf((float)(n + 1) * cstep * r);

        float Y[9];
        Y[0] = 1.0f;
        Y[1] = s3 * x;  Y[2] = s3 * y;  Y[3] = s3 * z;
        Y[4] = s15 * x * y;  Y[5] = s15 * y * z;
        Y[6] = 0.5f * s5 * (3.0f * z * z - 1.0f);
        Y[7] = s15 * x * z;  Y[8] = 0.5f * s15 * (x * x - y * y);

        // chunk-major layout: AYt[(e/32)*CHROWS*32 + row*32 + (e%32)]
        _Float16* ab = AYt + (size_t)(e >> 5) * (CHROWS * 32) + (e & 31);
        #pragma unroll
        for (int m = 0; m < 9; ++m)
            #pragma unroll
            for (int n = 0; n < 8; ++n)
                ab[(m * 8 + n) * 32] = (_Float16)(Y[m] * f[n]);
    } else if (b < PREP_EDGE_BLOCKS + PREP_WT_BLOCKS) {
        int idx = (b - PREP_EDGE_BLOCKS) * 256 + tid;   // < 98304
        int l   = idx >> 15;
        int rem = idx & 32767;
        int c   = rem >> 7;
        int k   = rem & 127;
        const float* W = (l == 0) ? W0 : ((l == 1) ? W1 : W2);
        Wt[idx] = (_Float16)W[k * 256 + c];
    } else {
        int i = (b - PREP_EDGE_BLOCKS - PREP_WT_BLOCKS) * 256 + tid;
        if (i > NPAD) return;
        int lo = 0, hi = N_EDGES;
        while (lo < hi) { int mid = (lo + hi) >> 1; if (esrc[mid] < i) lo = mid + 1; else hi = mid; }
        row_ptr[i] = lo;
    }
}

// ---------- E2: wave-per-node MFMA scatter-GEMM -> rho16 ----------
__global__ __launch_bounds__(256) void edge_gemm_kernel(
    const _Float16* __restrict__ AYt, const short* __restrict__ spE,
    const float* __restrict__ stab,  const int* __restrict__ row_ptr,
    _Float16* __restrict__ rho16)
{
    __shared__ _Float16 stabL[64 * 16];
    int tid = threadIdx.x;
    #pragma unroll
    for (int j = 0; j < 4; ++j) stabL[tid * 4 + j] = (_Float16)stab[tid * 4 + j];
    __syncthreads();

    const int wave = tid >> 6, lane = tid & 63;
    const int q = lane >> 4, nI = lane & 15;
    const int node = blockIdx.x * 4 + wave;      // pads have lo==hi
    const int lo = row_ptr[node], hi = row_ptr[node + 1];

    floatx4 acc[5];
    #pragma unroll
    for (int t = 0; t < 5; ++t) acc[t] = (floatx4){0.f, 0.f, 0.f, 0.f};

    for (int k0 = (lo & ~31); k0 < hi; k0 += 32) {
        short8 sp8 = *(const short8*)(spE + k0 + q * 8);
        half8 bfr;
        #pragma unroll
        for (int j = 0; j < 8; ++j) {
            int e = k0 + q * 8 + j;
            bool valid = (e >= lo) && (e < hi);
            int spv = valid ? (int)sp8[j] : 0;
            _Float16 v = stabL[spv * 16 + nI];
            bfr[j] = valid ? v : (_Float16)0;
        }
        const _Float16* cb = AYt + (size_t)(k0 >> 5) * (CHROWS * 32) + q * 8;
        #pragma unroll
        for (int t = 0; t < 5; ++t) {
            // rows 72..79 (t==4, nI>=8) overread into next chunk: garbage lands
            // only in output rows 72..79, which are store-masked below.
            half8 a = *(const half8*)(cb + (t * 16 + nI) * 32);
            acc[t] = __builtin_amdgcn_mfma_f32_16x16x32_f16(a, bfr, acc[t], 0, 0, 0);
        }
    }

    _Float16* rp = rho16 + (size_t)node * RHO_STRIDE;
    #pragma unroll
    for (int t = 0; t < 5; ++t)
        #pragma unroll
        for (int r = 0; r < 4; ++r) {
            int row = t * 16 + q * 4 + r;                 // C/D: row=q*4+reg, col=nI
            if (row < 72) {
                int m = row >> 3, nrad = row & 7;
                rp[m * NCH + nrad * 16 + nI] = (_Float16)acc[t][r];
            }
        }
}

// ---------- node kernel: MFMA GEMM, col-split x2 (16 nodes x 4 col-tiles/block) ----------
__global__ __launch_bounds__(256) void node_kernel(
    const _Float16* __restrict__ rho16, const _Float16* __restrict__ Wt,
    const float* __restrict__ stab, const int* __restrict__ species,
    float* __restrict__ out)
{
    const int tid  = threadIdx.x;
    const int wave = tid >> 6;
    const int lane = tid & 63;
    const int q    = lane >> 4;
    const int nI   = lane & 15;
    const int ng   = blockIdx.x >> 1;
    const int cbh  = blockIdx.x & 1;
    const int node0 = ng * 16;
    const int ct = cbh * 4 + wave;     // x-col tile 0..7 -> cols 16*ct..16*ct+15

    if (cbh == 0) {   // head: cols 0..143 (senc | rho m=0)
        int nn = tid >> 4;
        int node = node0 + nn;
        if (node < N_NODES) {
            int c0 = (tid & 15) * 9;
            float* o = out + (size_t)node * OUT_COLS;
            const _Float16* r0 = rho16 + (size_t)node * RHO_STRIDE;
            int sp = species[node];
            #pragma unroll
            for (int j = 0; j < 9; ++j) {
                int c = c0 + j;
                o[c] = (c < 16) ? stab[sp * 16 + c] : (float)r0[c - 16];
            }
        }
    }

    const _Float16* Abase = rho16 + (size_t)(node0 + nI) * RHO_STRIDE + q * 8;
    const int   mstart[3] = {0, 1, 4};
    const int   mcount[3] = {1, 3, 5};
    const float scl[3] = {1.0f, 0.5773502691896258f, 0.4472135954999579f};

    #pragma unroll
    for (int l = 0; l < 3; ++l) {
        const _Float16* Wl = Wt + l * 32768;

        half8 Bf[2][4];                 // [half(x/y)][K]
        #pragma unroll
        for (int h = 0; h < 2; ++h) {
            int c = 16 * ct + nI + h * 128;
            const _Float16* bp = Wl + (size_t)c * NCH + q * 8;
            #pragma unroll
            for (int K = 0; K < 4; ++K)
                Bf[h][K] = *(const half8*)(bp + K * 32);
        }

        floatx4 P = {0.f, 0.f, 0.f, 0.f};

        #pragma unroll
        for (int mi = 0; mi < mcount[l]; ++mi) {
            const _Float16* ap = Abase + (mstart[l] + mi) * NCH;
            half8 Af[4];
            #pragma unroll
            for (int K = 0; K < 4; ++K) Af[K] = *(const half8*)(ap + K * 32);

            floatx4 Cx = {0.f, 0.f, 0.f, 0.f};
            floatx4 Cy = {0.f, 0.f, 0.f, 0.f};
            #pragma unroll
            for (int K = 0; K < 4; ++K) {
                Cx = __builtin_amdgcn_mfma_f32_16x16x32_f16(Af[K], Bf[0][K], Cx, 0, 0, 0);
                Cy = __builtin_amdgcn_mfma_f32_16x16x32_f16(Af[K], Bf[1][K], Cy, 0, 0, 0);
            }
            P += Cx * Cy;
        }

        int c = 144 + l * NCH + 16 * ct + nI;
        #pragma unroll
        for (int r = 0; r < 4; ++r) {
            int node = node0 + q * 4 + r;
            if (node < N_NODES)
                out[(size_t)node * OUT_COLS + c] = P[r] * scl[l];
        }
    }
}

// ---------- fallback path (small-ws): R3 kernels ----------
__global__ __launch_bounds__(256) void rowptr_kernel(
    const int* __restrict__ esrc, int* __restrict__ row_ptr)
{
    int i = blockIdx.x * 256 + threadIdx.x;
    if (i > NPAD) return;
    int lo = 0, hi = N_EDGES;
    while (lo < hi) { int mid = (lo + hi) >> 1; if (esrc[mid] < i) lo = mid + 1; else hi = mid; }
    row_ptr[i] = lo;
}

__global__ __launch_bounds__(256) void wt_kernel(
    const float* __restrict__ W0, const float* __restrict__ W1,
    const float* __restrict__ W2, _Float16* __restrict__ Wt)
{
    int idx = blockIdx.x * 256 + threadIdx.x;
    if (idx >= 98304) return;
    int l   = idx >> 15;
    int rem = idx & 32767;
    int c   = rem >> 7;
    int k   = rem & 127;
    const float* W = (l == 0) ? W0 : ((l == 1) ? W1 : W2);
    Wt[idx] = (_Float16)W[k * 256 + c];
}

__global__ __launch_bounds__(128) void edge_kernel(
    const float* __restrict__ dist, const float* __restrict__ vec,
    const float* __restrict__ sw,   const float* __restrict__ stab,
    const int* __restrict__ species, const int* __restrict__ edst,
    const int* __restrict__ row_ptr, _Float16* __restrict__ rho16)
{
    const int node = blockIdx.x;
    const int t = threadIdx.x;
    const int n = t >> 4;
    const int s = t & 15;
    const float coefn = (float)(n + 1) * (3.14159265358979323846f / 5.0f);
    const float bnorm = 0.6324555320336759f;
    const float s3  = 1.7320508075688772f;
    const float s5  = 2.2360679774997896f;
    const float s15 = 3.872983346207417f;

    const int lo = row_ptr[node], hi = row_ptr[node + 1];
    float acc[9];
    #pragma unroll
    for (int m = 0; m < 9; ++m) acc[m] = 0.0f;

    for (int e = lo; e < hi; ++e) {
        float r    = dist[e];
        float invr = 1.0f / r;
        float swv  = sw[e];
        float x = vec[3*e+0] * invr;
        float y = vec[3*e+1] * invr;
        float z = vec[3*e+2] * invr;
        int   sp = species[edst[e]];
        float sv = stab[sp * 16 + s];
        float D  = bnorm * __sinf(coefn * r) * invr * swv * sv;
        acc[0] += D;
        acc[1] += D * (s3 * x);
        acc[2] += D * (s3 * y);
        acc[3] += D * (s3 * z);
        acc[4] += D * (s15 * x * y);
        acc[5] += D * (s15 * y * z);
        acc[6] += D * (0.5f * s5 * (3.0f * z * z - 1.0f));
        acc[7] += D * (s15 * x * z);
        acc[8] += D * (0.5f * s15 * (x * x - y * y));
    }
    _Float16* rp = rho16 + (size_t)node * RHO_STRIDE + t;
    #pragma unroll
    for (int m = 0; m < 9; ++m) rp[m * NCH] = (_Float16)acc[m];
}

extern "C" void kernel_launch(void* const* d_in, const int* in_sizes, int n_in,
                              void* d_out, int out_size, void* d_ws, size_t ws_size,
                              hipStream_t stream) {
    const float* distances = (const float*)d_in[0];
    const float* vec       = (const float*)d_in[1];
    const float* sw        = (const float*)d_in[2];
    const float* stab      = (const float*)d_in[3];
    const float* W0        = (const float*)d_in[4];
    const float* W1        = (const float*)d_in[5];
    const float* W2        = (const float*)d_in[6];
    const int*   species   = (const int*)d_in[7];
    const int*   esrc      = (const int*)d_in[8];
    const int*   edst      = (const int*)d_in[9];
    float* out = (float*)d_out;

    _Float16* rho16  = (_Float16*)d_ws;
    _Float16* Wt     = (_Float16*)((char*)d_ws + WT_OFF);
    int*      rowptr = (int*)((char*)d_ws + RP_OFF);

    if (ws_size >= WS_NEEDED) {
        short*    spE = (short*)((char*)d_ws + SPE_OFF);
        _Float16* AYt = (_Float16*)((char*)d_ws + AYT_OFF);
        prep_kernel<<<PREP_BLOCKS, 256, 0, stream>>>(
            distances, vec, sw, species, edst, esrc, W0, W1, W2,
            AYt, spE, Wt, rowptr);
        edge_gemm_kernel<<<NPAD / 4, 256, 0, stream>>>(AYt, spE, stab, rowptr, rho16);
    } else {
        rowptr_kernel<<<(NPAD + 256) / 256, 256, 0, stream>>>(esrc, rowptr);
        wt_kernel<<<(98304 + 255) / 256, 256, 0, stream>>>(W0, W1, W2, Wt);
        edge_kernel<<<NPAD, 128, 0, stream>>>(distances, vec, sw, stab, species,
                                              edst, rowptr, rho16);
    }

    node_kernel<<<(NPAD / 16) * 2, 256, 0, stream>>>(rho16, Wt, stab, species, out);
}

// Round 6
// 143.017 us; speedup vs baseline: 1.2525x; 1.2525x over previous
//
#include <hip/hip_runtime.h>
#include <math.h>

#define N_NODES 15000
#define NPAD    15008          // 938 node-groups * 16
#define N_EDGES 300000
#define NCH     128
#define OUT_COLS 528           // 16 + 128 + 3*128
#define ES      300032         // padded edge count (mult of 32)
#define NCHUNK  (ES / 32)      // 9376
#define CHROWS  72             // rows per chunk in AYt

// AF: A-fragment-ordered rho. AF[ng][m][K][lane(q*16+nI)][j8]
//   value rho[node0+nI][k], k = K*32 + q*8 + j. Per ng: 9*4*512 = 18432 halves.
#define AF_GROUP (9 * 4 * 512)

typedef _Float16 half8   __attribute__((ext_vector_type(8)));
typedef short    short8  __attribute__((ext_vector_type(8)));
typedef float    floatx4 __attribute__((ext_vector_type(4)));

// ---- workspace layout ----
#define AF_BYTES    ((size_t)(NPAD / 16) * AF_GROUP * 2)     // 34,578,432
#define WF_OFF      AF_BYTES
#define WF_BYTES    (3 * 256 * 128 * 2)                      // 196,608
#define RP_OFF      (WF_OFF + WF_BYTES)
#define RP_BYTES    61440
#define SPE_OFF     (RP_OFF + RP_BYTES)
#define SPE_BYTES   ((size_t)ES * 2)                         // 600,064
#define AYT_OFF     (SPE_OFF + SPE_BYTES)
#define AYT_BYTES   ((size_t)NCHUNK * CHROWS * 32 * 2 + 4096)
#define WS_NEEDED   (AYT_OFF + AYT_BYTES)                    // ~78.6 MB

// block-role boundaries for fused prep kernel
#define PREP_EDGE_BLOCKS 1172          // ceil(300000/256)
#define PREP_WF_BLOCKS   384           // 98304/256
#define PREP_RP_BLOCKS   59            // ceil(15009/256)
#define PREP_BLOCKS (PREP_EDGE_BLOCKS + PREP_WF_BLOCKS + PREP_RP_BLOCKS)

// WF position for (l, c, k): c = h*128 + ct*16 + nI, k = K*32 + q*8 + j
__device__ __forceinline__ size_t wf_pos(int l, int c, int k) {
    int h = c >> 7, cc = c & 127;
    int ct = cc >> 4, nI = cc & 15;
    int K = k >> 5, q = (k >> 3) & 3, j = k & 7;
    return ((size_t)((((l * 8 + ct) * 2 + h) * 4 + K) * 64 + q * 16 + nI)) * 8 + j;
}

// AF position for (node, m, k)
__device__ __forceinline__ size_t af_pos(int node, int m, int k) {
    int ng = node >> 4, n16 = node & 15;
    int K = k >> 5, q = (k >> 3) & 3, j = k & 7;
    return (size_t)ng * AF_GROUP + ((size_t)((m * 4 + K) * 64 + q * 16 + n16)) * 8 + j;
}

// ---------- fused prep: edge geometry -> AYt/spE | WF transpose | row_ptr ----------
__global__ __launch_bounds__(256) void prep_kernel(
    const float* __restrict__ dist, const float* __restrict__ vec,
    const float* __restrict__ sw,   const int* __restrict__ species,
    const int* __restrict__ edst,   const int* __restrict__ esrc,
    const float* __restrict__ W0, const float* __restrict__ W1,
    const float* __restrict__ W2,
    _Float16* __restrict__ AYt, short* __restrict__ spE,
    _Float16* __restrict__ WF,  int* __restrict__ row_ptr)
{
    const int b = blockIdx.x, tid = threadIdx.x;
    if (b < PREP_EDGE_BLOCKS) {
        int e = b * 256 + tid;
        if (e >= N_EDGES) return;

        const float bnorm = 0.6324555320336759f;   // sqrt(2/cutoff)
        const float s3  = 1.7320508075688772f;
        const float s5  = 2.2360679774997896f;
        const float s15 = 3.872983346207417f;
        const float cstep = 3.14159265358979323846f / 5.0f;

        float r    = dist[e];
        float invr = 1.0f / r;
        float g    = bnorm * invr * sw[e];
        float x = vec[3*e+0] * invr;
        float y = vec[3*e+1] * invr;
        float z = vec[3*e+2] * invr;

        spE[e] = (short)species[edst[e]];

        float f[8];
        #pragma unroll
        for (int n = 0; n < 8; ++n)
            f[n] = g * __sinf((float)(n + 1) * cstep * r);

        float Y[9];
        Y[0] = 1.0f;
        Y[1] = s3 * x;  Y[2] = s3 * y;  Y[3] = s3 * z;
        Y[4] = s15 * x * y;  Y[5] = s15 * y * z;
        Y[6] = 0.5f * s5 * (3.0f * z * z - 1.0f);
        Y[7] = s15 * x * z;  Y[8] = 0.5f * s15 * (x * x - y * y);

        // chunk-major: AYt[(e/32)*CHROWS*32 + row*32 + (e%32)]
        _Float16* ab = AYt + (size_t)(e >> 5) * (CHROWS * 32) + (e & 31);
        #pragma unroll
        for (int m = 0; m < 9; ++m)
            #pragma unroll
            for (int n = 0; n < 8; ++n)
                ab[(m * 8 + n) * 32] = (_Float16)(Y[m] * f[n]);
    } else if (b < PREP_EDGE_BLOCKS + PREP_WF_BLOCKS) {
        int idx = (b - PREP_EDGE_BLOCKS) * 256 + tid;   // < 98304
        int l = idx >> 15;
        int c = (idx >> 7) & 255;
        int k = idx & 127;
        const float* W = (l == 0) ? W0 : ((l == 1) ? W1 : W2);
        WF[wf_pos(l, c, k)] = (_Float16)W[k * 256 + c];
    } else {
        int i = (b - PREP_EDGE_BLOCKS - PREP_WF_BLOCKS) * 256 + tid;
        if (i > NPAD) return;
        int lo = 0, hi = N_EDGES;
        while (lo < hi) { int mid = (lo + hi) >> 1; if (esrc[mid] < i) lo = mid + 1; else hi = mid; }
        row_ptr[i] = lo;
    }
}

// ---------- E2: wave-per-node MFMA scatter-GEMM -> AF ----------
__global__ __launch_bounds__(256) void edge_gemm_kernel(
    const _Float16* __restrict__ AYt, const short* __restrict__ spE,
    const float* __restrict__ stab,  const int* __restrict__ row_ptr,
    _Float16* __restrict__ AF)
{
    __shared__ _Float16 stabL[64 * 16];
    int tid = threadIdx.x;
    #pragma unroll
    for (int j = 0; j < 4; ++j) stabL[tid * 4 + j] = (_Float16)stab[tid * 4 + j];
    __syncthreads();

    const int wave = tid >> 6, lane = tid & 63;
    const int q = lane >> 4, nI = lane & 15;
    const int node = blockIdx.x * 4 + wave;      // pads have lo==hi
    const int lo = row_ptr[node], hi = row_ptr[node + 1];

    floatx4 acc[5];
    #pragma unroll
    for (int t = 0; t < 5; ++t) acc[t] = (floatx4){0.f, 0.f, 0.f, 0.f};

    for (int k0 = (lo & ~31); k0 < hi; k0 += 32) {
        short8 sp8 = *(const short8*)(spE + k0 + q * 8);
        half8 bfr;
        #pragma unroll
        for (int j = 0; j < 8; ++j) {
            int e = k0 + q * 8 + j;
            bool valid = (e >= lo) && (e < hi);
            int spv = valid ? (int)sp8[j] : 0;
            _Float16 v = stabL[spv * 16 + nI];
            bfr[j] = valid ? v : (_Float16)0;
        }
        const _Float16* cb = AYt + (size_t)(k0 >> 5) * (CHROWS * 32) + q * 8;
        #pragma unroll
        for (int t = 0; t < 5; ++t) {
            // rows 72..79 (t==4) overread into next chunk; store-masked below.
            half8 a = *(const half8*)(cb + (t * 16 + nI) * 32);
            acc[t] = __builtin_amdgcn_mfma_f32_16x16x32_f16(a, bfr, acc[t], 0, 0, 0);
        }
    }

    // store into A-fragment layout: value = rho[node][k], k = nrad*16 + s (s = nI)
    #pragma unroll
    for (int t = 0; t < 5; ++t)
        #pragma unroll
        for (int r = 0; r < 4; ++r) {
            int row = t * 16 + q * 4 + r;
            if (row < 72) {
                int m = row >> 3, nrad = row & 7;
                AF[af_pos(node, m, nrad * 16 + nI)] = (_Float16)acc[t][r];
            }
        }
}

// ---------- node kernel: MFMA GEMM, fragment-direct coalesced loads ----------
// 938 blocks x 256 thr; 16 nodes/block; wave owns x-col tiles {2w,2w+1} + y partners.
__global__ __launch_bounds__(256) void node_kernel(
    const _Float16* __restrict__ AF, const _Float16* __restrict__ WF,
    const float* __restrict__ stab, const int* __restrict__ species,
    float* __restrict__ out)
{
    const int tid  = threadIdx.x;
    const int wave = tid >> 6;
    const int lane = tid & 63;
    const int q    = lane >> 4;
    const int nI   = lane & 15;
    const int ng   = blockIdx.x;
    const int node0 = ng * 16;

    {   // head: cols 0..143 (senc | rho m=0)
        int nn = tid >> 4;
        int node = node0 + nn;
        if (node < N_NODES) {
            int c0 = (tid & 15) * 9;
            float* o = out + (size_t)node * OUT_COLS;
            int sp = species[node];
            #pragma unroll
            for (int j = 0; j < 9; ++j) {
                int c = c0 + j;
                float v;
                if (c < 16) v = stab[sp * 16 + c];
                else        v = (float)AF[af_pos(node, 0, c - 16)];
                o[c] = v;
            }
        }
    }

    const _Float16* afg = AF + (size_t)ng * AF_GROUP;
    const int   mstart[3] = {0, 1, 4};
    const int   mcount[3] = {1, 3, 5};
    const float scl[3] = {1.0f, 0.5773502691896258f, 0.4472135954999579f};

    #pragma unroll
    for (int l = 0; l < 3; ++l) {
        half8 Bf[2][2][4];              // [cp][half(x/y)][K] — coalesced 1KB loads
        #pragma unroll
        for (int cp = 0; cp < 2; ++cp)
            #pragma unroll
            for (int h = 0; h < 2; ++h) {
                int ct = 2 * wave + cp;
                const _Float16* bp = WF +
                    ((size_t)((((l * 8 + ct) * 2 + h) * 4) * 64 + lane)) * 8;
                #pragma unroll
                for (int K = 0; K < 4; ++K)
                    Bf[cp][h][K] = *(const half8*)(bp + (size_t)K * 512);
            }

        floatx4 P0 = {0.f, 0.f, 0.f, 0.f};
        floatx4 P1 = {0.f, 0.f, 0.f, 0.f};

        #pragma unroll
        for (int mi = 0; mi < mcount[l]; ++mi) {
            int m = mstart[l] + mi;
            const _Float16* ap = afg + ((size_t)(m * 4) * 64 + lane) * 8;
            half8 Af[4];
            #pragma unroll
            for (int K = 0; K < 4; ++K)
                Af[K] = *(const half8*)(ap + (size_t)K * 512);   // coalesced 1KB

            #pragma unroll
            for (int cp = 0; cp < 2; ++cp) {
                floatx4 Cx = {0.f, 0.f, 0.f, 0.f};
                floatx4 Cy = {0.f, 0.f, 0.f, 0.f};
                #pragma unroll
                for (int K = 0; K < 4; ++K) {
                    Cx = __builtin_amdgcn_mfma_f32_16x16x32_f16(Af[K], Bf[cp][0][K], Cx, 0, 0, 0);
                    Cy = __builtin_amdgcn_mfma_f32_16x16x32_f16(Af[K], Bf[cp][1][K], Cy, 0, 0, 0);
                }
                if (cp == 0) P0 += Cx * Cy; else P1 += Cx * Cy;
            }
        }

        #pragma unroll
        for (int cp = 0; cp < 2; ++cp) {
            floatx4 P = cp ? P1 : P0;
            int c = 144 + l * NCH + 16 * (2 * wave + cp) + nI;
            #pragma unroll
            for (int r = 0; r < 4; ++r) {
                int node = node0 + q * 4 + r;
                if (node < N_NODES)
                    out[(size_t)node * OUT_COLS + c] = P[r] * scl[l];
            }
        }
    }
}

// ---------- fallback path (small ws): produces same AF/WF layouts ----------
__global__ __launch_bounds__(256) void rowptr_kernel(
    const int* __restrict__ esrc, int* __restrict__ row_ptr)
{
    int i = blockIdx.x * 256 + threadIdx.x;
    if (i > NPAD) return;
    int lo = 0, hi = N_EDGES;
    while (lo < hi) { int mid = (lo + hi) >> 1; if (esrc[mid] < i) lo = mid + 1; else hi = mid; }
    row_ptr[i] = lo;
}

__global__ __launch_bounds__(256) void wf_kernel(
    const float* __restrict__ W0, const float* __restrict__ W1,
    const float* __restrict__ W2, _Float16* __restrict__ WF)
{
    int idx = blockIdx.x * 256 + threadIdx.x;
    if (idx >= 98304) return;
    int l = idx >> 15;
    int c = (idx >> 7) & 255;
    int k = idx & 127;
    const float* W = (l == 0) ? W0 : ((l == 1) ? W1 : W2);
    WF[wf_pos(l, c, k)] = (_Float16)W[k * 256 + c];
}

__global__ __launch_bounds__(128) void edge_kernel(
    const float* __restrict__ dist, const float* __restrict__ vec,
    const float* __restrict__ sw,   const float* __restrict__ stab,
    const int* __restrict__ species, const int* __restrict__ edst,
    const int* __restrict__ row_ptr, _Float16* __restrict__ AF)
{
    const int node = blockIdx.x;
    const int t = threadIdx.x;          // k-channel 0..127
    const int n = t >> 4;
    const int s = t & 15;
    const float coefn = (float)(n + 1) * (3.14159265358979323846f / 5.0f);
    const float bnorm = 0.6324555320336759f;
    const float s3  = 1.7320508075688772f;
    const float s5  = 2.2360679774997896f;
    const float s15 = 3.872983346207417f;

    const int lo = row_ptr[node], hi = row_ptr[node + 1];
    float acc[9];
    #pragma unroll
    for (int m = 0; m < 9; ++m) acc[m] = 0.0f;

    for (int e = lo; e < hi; ++e) {
        float r    = dist[e];
        float invr = 1.0f / r;
        float swv  = sw[e];
        float x = vec[3*e+0] * invr;
        float y = vec[3*e+1] * invr;
        float z = vec[3*e+2] * invr;
        int   sp = species[edst[e]];
        float sv = stab[sp * 16 + s];
        float D  = bnorm * __sinf(coefn * r) * invr * swv * sv;
        acc[0] += D;
        acc[1] += D * (s3 * x);
        acc[2] += D * (s3 * y);
        acc[3] += D * (s3 * z);
        acc[4] += D * (s15 * x * y);
        acc[5] += D * (s15 * y * z);
        acc[6] += D * (0.5f * s5 * (3.0f * z * z - 1.0f));
        acc[7] += D * (s15 * x * z);
        acc[8] += D * (0.5f * s15 * (x * x - y * y));
    }
    #pragma unroll
    for (int m = 0; m < 9; ++m)
        AF[af_pos(node, m, t)] = (_Float16)acc[m];
}

extern "C" void kernel_launch(void* const* d_in, const int* in_sizes, int n_in,
                              void* d_out, int out_size, void* d_ws, size_t ws_size,
                              hipStream_t stream) {
    const float* distances = (const float*)d_in[0];
    const float* vec       = (const float*)d_in[1];
    const float* sw        = (const float*)d_in[2];
    const float* stab      = (const float*)d_in[3];
    const float* W0        = (const float*)d_in[4];
    const float* W1        = (const float*)d_in[5];
    const float* W2        = (const float*)d_in[6];
    const int*   species   = (const int*)d_in[7];
    const int*   esrc      = (const int*)d_in[8];
    const int*   edst      = (const int*)d_in[9];
    float* out = (float*)d_out;

    _Float16* AF     = (_Float16*)d_ws;
    _Float16* WF     = (_Float16*)((char*)d_ws + WF_OFF);
    int*      rowptr = (int*)((char*)d_ws + RP_OFF);

    if (ws_size >= WS_NEEDED) {
        short*    spE = (short*)((char*)d_ws + SPE_OFF);
        _Float16* AYt = (_Float16*)((char*)d_ws + AYT_OFF);
        prep_kernel<<<PREP_BLOCKS, 256, 0, stream>>>(
            distances, vec, sw, species, edst, esrc, W0, W1, W2,
            AYt, spE, WF, rowptr);
        edge_gemm_kernel<<<NPAD / 4, 256, 0, stream>>>(AYt, spE, stab, rowptr, AF);
    } else {
        rowptr_kernel<<<(NPAD + 256) / 256, 256, 0, stream>>>(esrc, rowptr);
        wf_kernel<<<(98304 + 255) / 256, 256, 0, stream>>>(W0, W1, W2, WF);
        edge_kernel<<<NPAD, 128, 0, stream>>>(distances, vec, sw, stab, species,
                                              edst, rowptr, AF);
    }

    node_kernel<<<NPAD / 16, 256, 0, stream>>>(AF, WF, stab, species, out);
}

// Round 7
// 123.705 us; speedup vs baseline: 1.4480x; 1.1561x over previous
//
#include <hip/hip_runtime.h>
#include <math.h>

#define N_NODES 15000
#define NPAD    15008          // 938 node-groups * 16
#define N_EDGES 300000
#define NCH     128
#define OUT_COLS 528           // 16 + 128 + 3*128
#define ES      300032         // padded edge count (mult of 32)
#define NCHUNK  (ES / 32)      // 9376
#define CHROWS  72             // rows per chunk in AYt

typedef _Float16 half8   __attribute__((ext_vector_type(8)));
typedef short    short8  __attribute__((ext_vector_type(8)));
typedef float    floatx4 __attribute__((ext_vector_type(4)));

// ---- workspace layout (no AF buffer anymore — rho lives in LDS only) ----
#define WF_BYTES    (3 * 256 * 128 * 2)                      // 196,608
#define RP_OFF      WF_BYTES
#define RP_BYTES    61440
#define SPE_OFF     (RP_OFF + RP_BYTES)                      // 258,048
#define SPE_BYTES   ((size_t)ES * 2)                         // 600,064
#define AYT_OFF     (SPE_OFF + SPE_BYTES)                    // 858,112 (64B-mult)
#define AYT_BYTES   ((size_t)NCHUNK * CHROWS * 32 * 2 + 4096)

// block-role boundaries for fused prep kernel
#define PREP_EDGE_BLOCKS 1172          // ceil(300000/256)
#define PREP_WF_BLOCKS   384           // 98304/256
#define PREP_RP_BLOCKS   59            // ceil(15009/256)
#define PREP_BLOCKS (PREP_EDGE_BLOCKS + PREP_WF_BLOCKS + PREP_RP_BLOCKS)

// WF position for (l, c, k): c = h*128 + ct*16 + nI, k = K*32 + q*8 + j
__device__ __forceinline__ size_t wf_pos(int l, int c, int k) {
    int h = c >> 7, cc = c & 127;
    int ct = cc >> 4, nI = cc & 15;
    int K = k >> 5, q = (k >> 3) & 3, j = k & 7;
    return ((size_t)((((l * 8 + ct) * 2 + h) * 4 + K) * 64 + q * 16 + nI)) * 8 + j;
}

// ---------- fused prep: edge geometry -> AYt/spE | WF transpose | row_ptr ----------
__global__ __launch_bounds__(256) void prep_kernel(
    const float* __restrict__ dist, const float* __restrict__ vec,
    const float* __restrict__ sw,   const int* __restrict__ species,
    const int* __restrict__ edst,   const int* __restrict__ esrc,
    const float* __restrict__ W0, const float* __restrict__ W1,
    const float* __restrict__ W2,
    _Float16* __restrict__ AYt, short* __restrict__ spE,
    _Float16* __restrict__ WF,  int* __restrict__ row_ptr)
{
    const int b = blockIdx.x, tid = threadIdx.x;
    if (b < PREP_EDGE_BLOCKS) {
        int e = b * 256 + tid;
        if (e >= N_EDGES) return;

        const float bnorm = 0.6324555320336759f;   // sqrt(2/cutoff)
        const float s3  = 1.7320508075688772f;
        const float s5  = 2.2360679774997896f;
        const float s15 = 3.872983346207417f;
        const float cstep = 3.14159265358979323846f / 5.0f;

        float r    = dist[e];
        float invr = 1.0f / r;
        float g    = bnorm * invr * sw[e];
        float x = vec[3*e+0] * invr;
        float y = vec[3*e+1] * invr;
        float z = vec[3*e+2] * invr;

        spE[e] = (short)species[edst[e]];

        float f[8];
        #pragma unroll
        for (int n = 0; n < 8; ++n)
            f[n] = g * __sinf((float)(n + 1) * cstep * r);

        float Y[9];
        Y[0] = 1.0f;
        Y[1] = s3 * x;  Y[2] = s3 * y;  Y[3] = s3 * z;
        Y[4] = s15 * x * y;  Y[5] = s15 * y * z;
        Y[6] = 0.5f * s5 * (3.0f * z * z - 1.0f);
        Y[7] = s15 * x * z;  Y[8] = 0.5f * s15 * (x * x - y * y);

        // chunk-major: AYt[(e/32)*CHROWS*32 + row*32 + (e%32)]
        _Float16* ab = AYt + (size_t)(e >> 5) * (CHROWS * 32) + (e & 31);
        #pragma unroll
        for (int m = 0; m < 9; ++m)
            #pragma unroll
            for (int n = 0; n < 8; ++n)
                ab[(m * 8 + n) * 32] = (_Float16)(Y[m] * f[n]);
    } else if (b < PREP_EDGE_BLOCKS + PREP_WF_BLOCKS) {
        int idx = (b - PREP_EDGE_BLOCKS) * 256 + tid;   // < 98304
        int l = idx >> 15;
        int c = (idx >> 7) & 255;
        int k = idx & 127;
        const float* W = (l == 0) ? W0 : ((l == 1) ? W1 : W2);
        WF[wf_pos(l, c, k)] = (_Float16)W[k * 256 + c];
    } else {
        int i = (b - PREP_EDGE_BLOCKS - PREP_WF_BLOCKS) * 256 + tid;
        if (i > NPAD) return;
        int lo = 0, hi = N_EDGES;
        while (lo < hi) { int mid = (lo + hi) >> 1; if (esrc[mid] < i) lo = mid + 1; else hi = mid; }
        row_ptr[i] = lo;
    }
}

// ---------- fused main: edge scatter-GEMM (-> LDS) + node GEMM ----------
// 938 blocks x 256 thr; block owns 16 nodes. Phase 1: wave w runs the
// edge-GEMM for nodes node0+4w..+3, C-fragments parked in LDS in A-fragment
// order (row stride 136 halves = 272B -> conflict-light). Phase 2: node GEMM
// reads A from LDS (ds_read_b128), B from L2-resident WF; P = sum_m Cx*Cy.
__global__ __launch_bounds__(256) void main_kernel(
    const _Float16* __restrict__ AYt, const short* __restrict__ spE,
    const float* __restrict__ stab,  const int* __restrict__ row_ptr,
    const _Float16* __restrict__ WF, const int* __restrict__ species,
    float* __restrict__ out)
{
    __shared__ _Float16 stabL[64 * 16];                 // 2 KB
    __shared__ __align__(16) _Float16 srho[144 * 136];  // 39,168 B

    const int tid  = threadIdx.x;
    const int wave = tid >> 6;
    const int lane = tid & 63;
    const int q    = lane >> 4;
    const int nI   = lane & 15;
    const int node0 = blockIdx.x * 16;

    #pragma unroll
    for (int j = 0; j < 4; ++j) stabL[tid * 4 + j] = (_Float16)stab[tid * 4 + j];
    __syncthreads();

    // ---- phase 1: edge scatter-GEMM, 4 nodes per wave ----
    for (int i = 0; i < 4; ++i) {
        const int n16 = 4 * wave + i;
        const int node = node0 + n16;                   // pads: lo==hi -> zeros
        const int lo = row_ptr[node], hi = row_ptr[node + 1];

        floatx4 acc[5];
        #pragma unroll
        for (int t = 0; t < 5; ++t) acc[t] = (floatx4){0.f, 0.f, 0.f, 0.f};

        for (int k0 = (lo & ~31); k0 < hi; k0 += 32) {
            short8 sp8 = *(const short8*)(spE + k0 + q * 8);
            half8 bfr;
            #pragma unroll
            for (int j = 0; j < 8; ++j) {
                int e = k0 + q * 8 + j;
                bool valid = (e >= lo) && (e < hi);
                int spv = valid ? (int)sp8[j] : 0;
                _Float16 v = stabL[spv * 16 + nI];
                bfr[j] = valid ? v : (_Float16)0;
            }
            const _Float16* cb = AYt + (size_t)(k0 >> 5) * (CHROWS * 32) + q * 8;
            #pragma unroll
            for (int t = 0; t < 5; ++t) {
                // t==4 rows 72..79 overread into next chunk (finite garbage);
                // those C rows are write-masked below.
                half8 a = *(const half8*)(cb + (t * 16 + nI) * 32);
                acc[t] = __builtin_amdgcn_mfma_f32_16x16x32_f16(a, bfr, acc[t], 0, 0, 0);
            }
        }

        // park C-fragments in LDS in A-fragment order:
        // value rho[node][m][k], k = nrad*16 + nI
        #pragma unroll
        for (int t = 0; t < 5; ++t)
            #pragma unroll
            for (int r = 0; r < 4; ++r) {
                int row = t * 16 + q * 4 + r;           // C/D: row=q*4+reg (+16t)
                if (row < 72) {
                    int m = row >> 3, nrad = row & 7;
                    int k = nrad * 16 + nI;
                    int K = k >> 5, qq = (k >> 3) & 3, j = k & 7;
                    srho[((m * 4 + K) * 4 + qq) * 136 + n16 * 8 + j] = (_Float16)acc[t][r];
                }
            }
    }
    __syncthreads();

    // ---- head: cols 0..15 senc, 16..143 rho m=0 ----
    {
        int nn = tid >> 4, c = tid & 15;
        int node = node0 + nn;
        if (node < N_NODES) {
            float* o = out + (size_t)node * OUT_COLS;
            o[c] = stab[species[node] * 16 + c];
            int c0 = c * 8;                              // k = c0..c0+7
            int K = c0 >> 5, qq = (c0 >> 3) & 3;
            half8 h = *(const half8*)&srho[(K * 4 + qq) * 136 + nn * 8];
            #pragma unroll
            for (int j = 0; j < 8; ++j) o[16 + c0 + j] = (float)h[j];
        }
    }

    // ---- phase 2: node GEMM from LDS A-fragments ----
    const int   mstart[3] = {0, 1, 4};
    const int   mcount[3] = {1, 3, 5};
    const float scl[3] = {1.0f, 0.5773502691896258f, 0.4472135954999579f};

    #pragma unroll
    for (int l = 0; l < 3; ++l) {
        half8 Bf[2][2][4];              // [cp][half(x/y)][K] — coalesced 1KB loads
        #pragma unroll
        for (int cp = 0; cp < 2; ++cp)
            #pragma unroll
            for (int h = 0; h < 2; ++h) {
                int ct = 2 * wave + cp;
                const _Float16* bp = WF +
                    ((size_t)((((l * 8 + ct) * 2 + h) * 4) * 64 + lane)) * 8;
                #pragma unroll
                for (int K = 0; K < 4; ++K)
                    Bf[cp][h][K] = *(const half8*)(bp + (size_t)K * 512);
            }

        floatx4 P0 = {0.f, 0.f, 0.f, 0.f};
        floatx4 P1 = {0.f, 0.f, 0.f, 0.f};

        #pragma unroll
        for (int mi = 0; mi < mcount[l]; ++mi) {
            int m = mstart[l] + mi;
            half8 Af[4];
            #pragma unroll
            for (int K = 0; K < 4; ++K)
                Af[K] = *(const half8*)&srho[((m * 4 + K) * 4 + q) * 136 + nI * 8];

            #pragma unroll
            for (int cp = 0; cp < 2; ++cp) {
                floatx4 Cx = {0.f, 0.f, 0.f, 0.f};
                floatx4 Cy = {0.f, 0.f, 0.f, 0.f};
                #pragma unroll
                for (int K = 0; K < 4; ++K) {
                    Cx = __builtin_amdgcn_mfma_f32_16x16x32_f16(Af[K], Bf[cp][0][K], Cx, 0, 0, 0);
                    Cy = __builtin_amdgcn_mfma_f32_16x16x32_f16(Af[K], Bf[cp][1][K], Cy, 0, 0, 0);
                }
                if (cp == 0) P0 += Cx * Cy; else P1 += Cx * Cy;
            }
        }

        #pragma unroll
        for (int cp = 0; cp < 2; ++cp) {
            floatx4 P = cp ? P1 : P0;
            int c = 144 + l * NCH + 16 * (2 * wave + cp) + nI;
            #pragma unroll
            for (int r = 0; r < 4; ++r) {
                int node = node0 + q * 4 + r;
                if (node < N_NODES)
                    out[(size_t)node * OUT_COLS + c] = P[r] * scl[l];
            }
        }
    }
}

extern "C" void kernel_launch(void* const* d_in, const int* in_sizes, int n_in,
                              void* d_out, int out_size, void* d_ws, size_t ws_size,
                              hipStream_t stream) {
    const float* distances = (const float*)d_in[0];
    const float* vec       = (const float*)d_in[1];
    const float* sw        = (const float*)d_in[2];
    const float* stab      = (const float*)d_in[3];
    const float* W0        = (const float*)d_in[4];
    const float* W1        = (const float*)d_in[5];
    const float* W2        = (const float*)d_in[6];
    const int*   species   = (const int*)d_in[7];
    const int*   esrc      = (const int*)d_in[8];
    const int*   edst      = (const int*)d_in[9];
    float* out = (float*)d_out;

    _Float16* WF     = (_Float16*)d_ws;
    int*      rowptr = (int*)((char*)d_ws + RP_OFF);
    short*    spE    = (short*)((char*)d_ws + SPE_OFF);
    _Float16* AYt    = (_Float16*)((char*)d_ws + AYT_OFF);

    prep_kernel<<<PREP_BLOCKS, 256, 0, stream>>>(
        distances, vec, sw, species, edst, esrc, W0, W1, W2,
        AYt, spE, WF, rowptr);
    main_kernel<<<NPAD / 16, 256, 0, stream>>>(
        AYt, spE, stab, rowptr, WF, species, out);
}

// Round 8
// 116.764 us; speedup vs baseline: 1.5341x; 1.0594x over previous
//
#include <hip/hip_runtime.h>
#include <math.h>

#define N_NODES 15000
#define NPAD    15008          // 938 node-groups * 16
#define N_EDGES 300000
#define NCH     128
#define OUT_COLS 528           // 16 + 128 + 3*128
#define ES      300032         // padded edge count (mult of 32)
#define NCHUNK  (ES / 32)      // 9376
#define YROWS   17             // rows per chunk in Yf: 9 Y + 8 f
#define CHB     (YROWS * 32)   // 544 halves = 1088 B per chunk

typedef _Float16 half8   __attribute__((ext_vector_type(8)));
typedef short    short8  __attribute__((ext_vector_type(8)));
typedef float    floatx4 __attribute__((ext_vector_type(4)));

// ---- workspace layout ----
#define WF_BYTES    (3 * 256 * 128 * 2)                      // 196,608
#define RP_OFF      WF_BYTES
#define RP_BYTES    61440
#define SPE_OFF     (RP_OFF + RP_BYTES)                      // 258,048
#define SPE_BYTES   ((size_t)ES * 2)                         // 600,064
#define YF_OFF      (SPE_OFF + SPE_BYTES)                    // 858,112 (16B-mult)
#define YF_BYTES    ((size_t)NCHUNK * CHB * 2 + 256)         // 10,201,344

// block-role boundaries for fused prep kernel
#define PREP_EDGE_BLOCKS 1172          // ceil(300000/256)
#define PREP_WF_BLOCKS   384           // 98304/256
#define PREP_RP_BLOCKS   59            // ceil(15009/256)
#define PREP_BLOCKS (PREP_EDGE_BLOCKS + PREP_WF_BLOCKS + PREP_RP_BLOCKS)

// WF position for (l, c, k): c = h*128 + ct*16 + nI, k = K*32 + q*8 + j
__device__ __forceinline__ size_t wf_pos(int l, int c, int k) {
    int h = c >> 7, cc = c & 127;
    int ct = cc >> 4, nI = cc & 15;
    int K = k >> 5, q = (k >> 3) & 3, j = k & 7;
    return ((size_t)((((l * 8 + ct) * 2 + h) * 4 + K) * 64 + q * 16 + nI)) * 8 + j;
}

// ---------- fused prep: edge factors -> Yf/spE | WF transpose | row_ptr ----------
__global__ __launch_bounds__(256) void prep_kernel(
    const float* __restrict__ dist, const float* __restrict__ vec,
    const float* __restrict__ sw,   const int* __restrict__ species,
    const int* __restrict__ edst,   const int* __restrict__ esrc,
    const float* __restrict__ W0, const float* __restrict__ W1,
    const float* __restrict__ W2,
    _Float16* __restrict__ Yf, short* __restrict__ spE,
    _Float16* __restrict__ WF,  int* __restrict__ row_ptr)
{
    const int b = blockIdx.x, tid = threadIdx.x;
    if (b < PREP_EDGE_BLOCKS) {
        int e = b * 256 + tid;
        if (e >= N_EDGES) return;

        const float bnorm = 0.6324555320336759f;   // sqrt(2/cutoff)
        const float s3  = 1.7320508075688772f;
        const float s5  = 2.2360679774997896f;
        const float s15 = 3.872983346207417f;
        const float cstep = 3.14159265358979323846f / 5.0f;

        float r    = dist[e];
        float invr = 1.0f / r;
        float g    = bnorm * invr * sw[e];
        float x = vec[3*e+0] * invr;
        float y = vec[3*e+1] * invr;
        float z = vec[3*e+2] * invr;

        spE[e] = (short)species[edst[e]];

        // Yf chunk block: rows 0..8 = Y[m], rows 9..16 = f[n]
        _Float16* yb = Yf + (size_t)(e >> 5) * CHB + (e & 31);
        yb[0 * 32] = (_Float16)1.0f;
        yb[1 * 32] = (_Float16)(s3 * x);
        yb[2 * 32] = (_Float16)(s3 * y);
        yb[3 * 32] = (_Float16)(s3 * z);
        yb[4 * 32] = (_Float16)(s15 * x * y);
        yb[5 * 32] = (_Float16)(s15 * y * z);
        yb[6 * 32] = (_Float16)(0.5f * s5 * (3.0f * z * z - 1.0f));
        yb[7 * 32] = (_Float16)(s15 * x * z);
        yb[8 * 32] = (_Float16)(0.5f * s15 * (x * x - y * y));
        #pragma unroll
        for (int n = 0; n < 8; ++n)
            yb[(9 + n) * 32] = (_Float16)(g * __sinf((float)(n + 1) * cstep * r));
    } else if (b < PREP_EDGE_BLOCKS + PREP_WF_BLOCKS) {
        int idx = (b - PREP_EDGE_BLOCKS) * 256 + tid;   // < 98304
        int l = idx >> 15;
        int c = (idx >> 7) & 255;
        int k = idx & 127;
        const float* W = (l == 0) ? W0 : ((l == 1) ? W1 : W2);
        WF[wf_pos(l, c, k)] = (_Float16)W[k * 256 + c];
    } else {
        int i = (b - PREP_EDGE_BLOCKS - PREP_WF_BLOCKS) * 256 + tid;
        if (i > NPAD) return;
        int lo = 0, hi = N_EDGES;
        while (lo < hi) { int mid = (lo + hi) >> 1; if (esrc[mid] < i) lo = mid + 1; else hi = mid; }
        row_ptr[i] = lo;
    }
}

// ---------- fused main: edge scatter-GEMM (-> LDS) + node GEMM ----------
// 938 blocks x 256 thr; block owns 16 nodes. Phase 1: wave w runs the
// edge-GEMM for nodes node0+4w..+3; A-fragments are rebuilt on the fly from
// the factored Yf block (a = Y[m]*f[n], packed fp16 mul); C-fragments parked
// in LDS in A-fragment order. Phase 2: node GEMM reads A from LDS
// (ds_read_b128), B from L2-resident WF; P = sum_m Cx*Cy.
__global__ __launch_bounds__(256) void main_kernel(
    const _Float16* __restrict__ Yf, const short* __restrict__ spE,
    const float* __restrict__ stab,  const int* __restrict__ row_ptr,
    const _Float16* __restrict__ WF, const int* __restrict__ species,
    float* __restrict__ out)
{
    __shared__ _Float16 stabL[64 * 16];                 // 2 KB
    __shared__ __align__(16) _Float16 srho[144 * 136];  // 39,168 B

    const int tid  = threadIdx.x;
    const int wave = tid >> 6;
    const int lane = tid & 63;
    const int q    = lane >> 4;
    const int nI   = lane & 15;
    const int node0 = blockIdx.x * 16;

    #pragma unroll
    for (int j = 0; j < 4; ++j) stabL[tid * 4 + j] = (_Float16)stab[tid * 4 + j];
    __syncthreads();

    // ---- phase 1: edge scatter-GEMM, 4 nodes per wave ----
    for (int i = 0; i < 4; ++i) {
        const int n16 = 4 * wave + i;
        const int node = node0 + n16;                   // pads: lo==hi -> zeros
        const int lo = row_ptr[node], hi = row_ptr[node + 1];

        floatx4 acc[5];
        #pragma unroll
        for (int t = 0; t < 5; ++t) acc[t] = (floatx4){0.f, 0.f, 0.f, 0.f};

        for (int k0 = (lo & ~31); k0 < hi; k0 += 32) {
            short8 sp8 = *(const short8*)(spE + k0 + q * 8);
            half8 bfr;
            #pragma unroll
            for (int j = 0; j < 8; ++j) {
                int e = k0 + q * 8 + j;
                bool valid = (e >= lo) && (e < hi);
                int spv = valid ? (int)sp8[j] : 0;
                _Float16 v = stabL[spv * 16 + nI];
                bfr[j] = valid ? v : (_Float16)0;
            }
            const _Float16* yb = Yf + (size_t)(k0 >> 5) * CHB + q * 8;
            #pragma unroll
            for (int t = 0; t < 5; ++t) {
                int row = t * 16 + nI;
                int m = row >> 3;      // 0..9; m==9 (rows 72..79) reads f-row 0:
                int n = row & 7;       // in-bounds garbage, C rows store-masked
                half8 Y8 = *(const half8*)(yb + m * 32);
                half8 F8 = *(const half8*)(yb + (9 + n) * 32);
                half8 a = Y8 * F8;
                acc[t] = __builtin_amdgcn_mfma_f32_16x16x32_f16(a, bfr, acc[t], 0, 0, 0);
            }
        }

        // park C-fragments in LDS in A-fragment order:
        // value rho[node][m][k], k = nrad*16 + nI
        #pragma unroll
        for (int t = 0; t < 5; ++t)
            #pragma unroll
            for (int r = 0; r < 4; ++r) {
                int row = t * 16 + q * 4 + r;           // C/D: row=q*4+reg (+16t)
                if (row < 72) {
                    int m = row >> 3, nrad = row & 7;
                    int k = nrad * 16 + nI;
                    int K = k >> 5, qq = (k >> 3) & 3, j = k & 7;
                    srho[((m * 4 + K) * 4 + qq) * 136 + n16 * 8 + j] = (_Float16)acc[t][r];
                }
            }
    }
    __syncthreads();

    // ---- head: cols 0..15 senc, 16..143 rho m=0 ----
    {
        int nn = tid >> 4, c = tid & 15;
        int node = node0 + nn;
        if (node < N_NODES) {
            float* o = out + (size_t)node * OUT_COLS;
            o[c] = stab[species[node] * 16 + c];
            int c0 = c * 8;                              // k = c0..c0+7
            int K = c0 >> 5, qq = (c0 >> 3) & 3;
            half8 h = *(const half8*)&srho[(K * 4 + qq) * 136 + nn * 8];
            #pragma unroll
            for (int j = 0; j < 8; ++j) o[16 + c0 + j] = (float)h[j];
        }
    }

    // ---- phase 2: node GEMM from LDS A-fragments ----
    const int   mstart[3] = {0, 1, 4};
    const int   mcount[3] = {1, 3, 5};
    const float scl[3] = {1.0f, 0.5773502691896258f, 0.4472135954999579f};

    #pragma unroll
    for (int l = 0; l < 3; ++l) {
        half8 Bf[2][2][4];              // [cp][half(x/y)][K] — coalesced 1KB loads
        #pragma unroll
        for (int cp = 0; cp < 2; ++cp)
            #pragma unroll
            for (int h = 0; h < 2; ++h) {
                int ct = 2 * wave + cp;
                const _Float16* bp = WF +
                    ((size_t)((((l * 8 + ct) * 2 + h) * 4) * 64 + lane)) * 8;
                #pragma unroll
                for (int K = 0; K < 4; ++K)
                    Bf[cp][h][K] = *(const half8*)(bp + (size_t)K * 512);
            }

        floatx4 P0 = {0.f, 0.f, 0.f, 0.f};
        floatx4 P1 = {0.f, 0.f, 0.f, 0.f};

        #pragma unroll
        for (int mi = 0; mi < mcount[l]; ++mi) {
            int m = mstart[l] + mi;
            half8 Af[4];
            #pragma unroll
            for (int K = 0; K < 4; ++K)
                Af[K] = *(const half8*)&srho[((m * 4 + K) * 4 + q) * 136 + nI * 8];

            #pragma unroll
            for (int cp = 0; cp < 2; ++cp) {
                floatx4 Cx = {0.f, 0.f, 0.f, 0.f};
                floatx4 Cy = {0.f, 0.f, 0.f, 0.f};
                #pragma unroll
                for (int K = 0; K < 4; ++K) {
                    Cx = __builtin_amdgcn_mfma_f32_16x16x32_f16(Af[K], Bf[cp][0][K], Cx, 0, 0, 0);
                    Cy = __builtin_amdgcn_mfma_f32_16x16x32_f16(Af[K], Bf[cp][1][K], Cy, 0, 0, 0);
                }
                if (cp == 0) P0 += Cx * Cy; else P1 += Cx * Cy;
            }
        }

        #pragma unroll
        for (int cp = 0; cp < 2; ++cp) {
            floatx4 P = cp ? P1 : P0;
            int c = 144 + l * NCH + 16 * (2 * wave + cp) + nI;
            #pragma unroll
            for (int r = 0; r < 4; ++r) {
                int node = node0 + q * 4 + r;
                if (node < N_NODES)
                    out[(size_t)node * OUT_COLS + c] = P[r] * scl[l];
            }
        }
    }
}

extern "C" void kernel_launch(void* const* d_in, const int* in_sizes, int n_in,
                              void* d_out, int out_size, void* d_ws, size_t ws_size,
                              hipStream_t stream) {
    const float* distances = (const float*)d_in[0];
    const float* vec       = (const float*)d_in[1];
    const float* sw        = (const float*)d_in[2];
    const float* stab      = (const float*)d_in[3];
    const float* W0        = (const float*)d_in[4];
    const float* W1        = (const float*)d_in[5];
    const float* W2        = (const float*)d_in[6];
    const int*   species   = (const int*)d_in[7];
    const int*   esrc      = (const int*)d_in[8];
    const int*   edst      = (const int*)d_in[9];
    float* out = (float*)d_out;

    _Float16* WF     = (_Float16*)d_ws;
    int*      rowptr = (int*)((char*)d_ws + RP_OFF);
    short*    spE    = (short*)((char*)d_ws + SPE_OFF);
    _Float16* Yf     = (_Float16*)((char*)d_ws + YF_OFF);

    prep_kernel<<<PREP_BLOCKS, 256, 0, stream>>>(
        distances, vec, sw, species, edst, esrc, W0, W1, W2,
        Yf, spE, WF, rowptr);
    main_kernel<<<NPAD / 16, 256, 0, stream>>>(
        Yf, spE, stab, rowptr, WF, species, out);
}